// Round 10
// baseline (119.839 us; speedup 1.0000x reference)
//
#include <hip/hip_runtime.h>
#include <hip/hip_bf16.h>

#define TPB 512
#define VPT 32
#define NDAT 16384  // N = T-1
#define TLEN 16385
#define NW (TPB / 64)  // 8 waves

__global__ __launch_bounds__(TPB) void vpl_kernel(
    const float* __restrict__ x, const float* __restrict__ params,
    float* __restrict__ out, int B) {
  const int b = blockIdx.x;
  const int tid = threadIdx.x;
  const int lane = tid & 63;
  const int wid = tid >> 6;

  const float r = params[0];
  const float ny = params[1];
  const bool rhalf = (r == 0.5f);

  const float* __restrict__ xr = x + (size_t)b * TLEN;

  float* out_coeffs = out;                                   // 2*B
  float* out_xhat = out + (size_t)2 * B + (size_t)b * NDAT;  // B*N
  float* out_res = out + (size_t)2 * B + (size_t)B * NDAT + (size_t)b * NDAT;
  float* out_r2 = out + (size_t)2 * B + (size_t)2 * B * NDAT;  // B

  __shared__ double wtot[NW];      // per-wave scan totals (fp64)
  __shared__ double sred[NW][5];   // per-wave reduction partials
  __shared__ float cbc[2];         // broadcast coeffs

  const int base = tid * VPT;  // this thread's contiguous chunk [base, base+32)

  // ---- load whole chunk into registers (33 independent loads) --------------
  const float x0 = xr[base];
  float xv[VPT];
#pragma unroll
  for (int j = 0; j < VPT; ++j) xv[j] = xr[base + 1 + j];  // max idx 16384 OK

  // ---- local trapezoid prefix (serial fp32, fixed order) -------------------
  float run[VPT];
  {
    float prev = x0, acc = 0.f;
#pragma unroll
    for (int j = 0; j < VPT; ++j) {
      acc += 0.5f * (prev + xv[j]);
      run[j] = acc;
      prev = xv[j];
    }
  }
  const float tot = run[VPT - 1];

  // ---- fp64 wave-inclusive scan of thread totals ---------------------------
  double t = (double)tot;
#pragma unroll
  for (int d = 1; d < 64; d <<= 1) {
    double o = __shfl_up(t, d, 64);
    if (lane >= d) t += o;
  }
  if (lane == 63) wtot[wid] = t;
  __syncthreads();

  double cross = 0.0;
#pragma unroll
  for (int w = 0; w < NW; ++w)
    if (w < wid) cross += wtot[w];
  // this thread's exclusive-prefix base for u (fp64 assembled, fp32 used)
  const float offf = (float)((double)ny + cross + (t - (double)tot));

  // ---- Gram/rhs partial sums (branch hoisted: powf never issues) -----------
  float s_u = 0.f, s_u2 = 0.f, s_u15 = 0.f, s_xu = 0.f, s_xv = 0.f;
  if (rhalf) {
#pragma unroll
    for (int j = 0; j < VPT; ++j) {
      const float uu = offf + run[j];
      const float vh = sqrtf(uu);
      const float xd = xv[j];
      s_u += uu;
      s_u2 = fmaf(uu, uu, s_u2);
      s_u15 = fmaf(uu, vh, s_u15);
      s_xu = fmaf(xd, uu, s_xu);
      s_xv = fmaf(xd, vh, s_xv);
    }
  } else {
#pragma unroll
    for (int j = 0; j < VPT; ++j) {
      const float uu = offf + run[j];
      const float vh = powf(uu, r);
      const float xd = xv[j];
      s_u += uu;
      s_u2 = fmaf(uu, uu, s_u2);
      s_u15 = fmaf(uu, vh, s_u15);
      s_xu = fmaf(xd, uu, s_xu);
      s_xv = fmaf(xd, vh, s_xv);
    }
  }

  // ---- block reduction of the 5 sums (fp64 tree) ---------------------------
  {
    double vals[5] = {(double)s_u, (double)s_u2, (double)s_u15, (double)s_xu,
                      (double)s_xv};
#pragma unroll
    for (int i = 0; i < 5; ++i) {
      double v = vals[i];
#pragma unroll
      for (int d = 32; d >= 1; d >>= 1) v += __shfl_down(v, d, 64);
      vals[i] = v;
    }
    if (lane == 0) {
#pragma unroll
      for (int i = 0; i < 5; ++i) sred[wid][i] = vals[i];
    }
  }
  __syncthreads();

  if (tid == 0) {
    double g[5];
#pragma unroll
    for (int i = 0; i < 5; ++i) {
      double s = 0.0;
#pragma unroll
      for (int w = 0; w < NW; ++w) s += sred[w][i];
      g[i] = s;
    }
    const double g11 = g[0];  // sum u       (= G[1][1] when r=0.5)
    const double g00 = g[1];  // sum u^2     (= G[0][0])
    const double g01 = g[2];  // sum u^{1+r} (= G[0][1])
    const double b0 = g[3];   // sum xd*u
    const double b1 = g[4];   // sum xd*u^r

    // Replicate jnp.linalg.pinv: fp32 SVD with rcond = 10*16384*eps = 0.01953125
    const double tr = g00 + g11;
    const double det = g00 * g11 - g01 * g01;
    const double disc = sqrt(fmax(tr * tr - 4.0 * det, 0.0));
    const double l1 = 0.5 * (tr + disc);
    const double l2 = (l1 > 0.0) ? fmax(det / l1, 0.0) : 0.0;
    const double s1 = sqrt(fmax(l1, 0.0));
    const double s2 = sqrt(l2);
    const double rcond = 0.01953125;

    double c0, c1;
    if (s2 > rcond * s1) {
      c0 = (g11 * b0 - g01 * b1) / det;  // rank-2 normal equations
      c1 = (g00 * b1 - g01 * b0) / det;
    } else if (s1 > 0.0) {
      // rank-1 truncated pinv: coeffs = ((b.e1)/l1) * e1, e1 ~ [l1-g11, g01]
      double w0 = l1 - g11, w1 = g01;
      double nrm = sqrt(w0 * w0 + w1 * w1);
      double e0, e1;
      if (nrm > 0.0) {
        e0 = w0 / nrm;
        e1 = w1 / nrm;
      } else {
        e0 = 1.0;
        e1 = 0.0;
      }
      const double gam = (b0 * e0 + b1 * e1) / l1;
      c0 = gam * e0;
      c1 = gam * e1;
    } else {
      c0 = 0.0;
      c1 = 0.0;
    }
    out_coeffs[2 * b] = (float)c0;
    out_coeffs[2 * b + 1] = (float)c1;
    cbc[0] = (float)c0;
    cbc[1] = (float)c1;
  }
  __syncthreads();
  const float c0 = cbc[0];
  const float c1 = cbc[1];

  // ---- outputs: per-quad compute + immediate float4 stores -----------------
  float r2f = 0.f;
  if (rhalf) {
#pragma unroll
    for (int q = 0; q < VPT / 4; ++q) {
      float xh[4], rs[4];
#pragma unroll
      for (int i = 0; i < 4; ++i) {
        const int j = q * 4 + i;
        const float uu = offf + run[j];  // bit-identical to Gram-pass uu
        const float vh = sqrtf(uu);
        xh[i] = fmaf(c0, uu, c1 * vh);
        rs[i] = xv[j] - xh[i];
        r2f = fmaf(rs[i], rs[i], r2f);
      }
      *reinterpret_cast<float4*>(out_xhat + base + 4 * q) =
          make_float4(xh[0], xh[1], xh[2], xh[3]);
      *reinterpret_cast<float4*>(out_res + base + 4 * q) =
          make_float4(rs[0], rs[1], rs[2], rs[3]);
    }
  } else {
#pragma unroll
    for (int q = 0; q < VPT / 4; ++q) {
      float xh[4], rs[4];
#pragma unroll
      for (int i = 0; i < 4; ++i) {
        const int j = q * 4 + i;
        const float uu = offf + run[j];
        const float vh = powf(uu, r);
        xh[i] = fmaf(c0, uu, c1 * vh);
        rs[i] = xv[j] - xh[i];
        r2f = fmaf(rs[i], rs[i], r2f);
      }
      *reinterpret_cast<float4*>(out_xhat + base + 4 * q) =
          make_float4(xh[0], xh[1], xh[2], xh[3]);
      *reinterpret_cast<float4*>(out_res + base + 4 * q) =
          make_float4(rs[0], rs[1], rs[2], rs[3]);
    }
  }

  // ---- reduce r2 (fp64 tree over fp32 per-thread partials) -----------------
  double r2 = (double)r2f;
#pragma unroll
  for (int d = 32; d >= 1; d >>= 1) r2 += __shfl_down(r2, d, 64);
  if (lane == 0) sred[wid][0] = r2;
  __syncthreads();
  if (tid == 0) {
    double s = 0.0;
#pragma unroll
    for (int w = 0; w < NW; ++w) s += sred[w][0];
    out_r2[b] = (float)s;
  }
}

extern "C" void kernel_launch(void* const* d_in, const int* in_sizes, int n_in,
                              void* d_out, int out_size, void* d_ws,
                              size_t ws_size, hipStream_t stream) {
  const float* x = (const float*)d_in[0];
  const float* params = (const float*)d_in[1];
  float* out = (float*)d_out;
  const int B = in_sizes[0] / TLEN;  // 512
  vpl_kernel<<<dim3(B), dim3(TPB), 0, stream>>>(x, params, out, B);
}